// Round 12
// baseline (218.311 us; speedup 1.0000x reference)
//
#include <hip/hip_runtime.h>
#include <hip/hip_bf16.h>
#include <math.h>

typedef _Float16 half4 __attribute__((ext_vector_type(4)));
typedef _Float16 half8 __attribute__((ext_vector_type(8)));
typedef float f32x4 __attribute__((ext_vector_type(4)));

#define NE 500000
#define ND 128
#define NNODES 100000
#define NT2 ((NE + 127) / 128)       // 3907 tiles of 128 edges
#define ZI_BLOCKS 12500              // prep: zi mirror part

// ---- merged prep: blocks [0,12500) build zi; [12500,12756) build w1p ----
// zi[node][256] = [z row | z2 row] fp16, contiguous 512B per node.
// w1p = W1 packed in MFMA B-frag order: i = ni*16384+nf*4096+ks*512+lane*8+j
//   holds W1[k][col], col = ni*64+nf*16+(lane&15), k = ks*32+(lane>>4)*8+j.
__global__ __launch_bounds__(256) void prep_all_kernel(
    const float* __restrict__ z, const float* __restrict__ z2,
    _Float16* __restrict__ zi,
    const float* __restrict__ W1, _Float16* __restrict__ w1p) {
    if (blockIdx.x < ZI_BLOCKS) {
        long t = (long)blockIdx.x * 256 + threadIdx.x;  // 3.2M threads, 8 elems
        long idx = t * 8;
        int node = (int)(idx >> 8), col = (int)(idx & 255);
        const float* src = (col < 128) ? (z + (long)node * 128 + col)
                                       : (z2 + (long)node * 128 + (col - 128));
        float4 a = *reinterpret_cast<const float4*>(src);
        float4 b = *reinterpret_cast<const float4*>(src + 4);
        half8 v;
        v[0] = (_Float16)a.x; v[1] = (_Float16)a.y;
        v[2] = (_Float16)a.z; v[3] = (_Float16)a.w;
        v[4] = (_Float16)b.x; v[5] = (_Float16)b.y;
        v[6] = (_Float16)b.z; v[7] = (_Float16)b.w;
        *reinterpret_cast<half8*>(zi + idx) = v;
    } else {
        int i = (blockIdx.x - ZI_BLOCKS) * 256 + threadIdx.x;   // 0..65535
        int j = i & 7;
        int lane = (i >> 3) & 63;
        int ks = (i >> 9) & 7;
        int nf = (i >> 12) & 3;
        int ni = i >> 14;
        int col = ni * 64 + nf * 16 + (lane & 15);
        int k = ks * 32 + (lane >> 4) * 8 + j;
        w1p[i] = (_Float16)W1[(long)k * 256 + col];
    }
}

// v12: 128-edge tile, 512 threads / 8 waves (2 row-halves x 4 col-quarters).
// Per-wave profile identical to r11 (16 edges, 64 acc, 32 B-loads, 128-reg
// budget) but B traffic per edge halves and same-ni wave pairs share L1.
// LDS 66KB -> 2 blocks/CU = 16 waves/CU (same occupancy as r11).
template<int MIRROR>
__global__ __launch_bounds__(512, 2) void edge_mlp_v12(
    const float* __restrict__ z, const float* __restrict__ z2,
    const _Float16* __restrict__ zi,
    const int* __restrict__ edge,
    const _Float16* __restrict__ w1p,
    const float* __restrict__ b1, const float* __restrict__ W2,
    const float* __restrict__ b2, float* __restrict__ out)
{
    __shared__ _Float16 xs[128 * 256];  // 64 KB, XOR-swizzled x-tile
    __shared__ float ps[4 * 128];       // 2 KB partials [ni][row]

    const int tid = threadIdx.x;
    const int lane = tid & 63;
    const int wv = tid >> 6;            // 0..7
    const int mi = wv >> 2;             // row half: rows [mi*64, mi*64+64)
    const int ni = wv & 3;              // col quarter: cols [ni*64, ni*64+64)
    const int l15 = lane & 15;
    const int l4 = lane >> 4;
    const long eb0 = (long)blockIdx.x * 128;

    // wave's 16 edges (rows wv*16..wv*16+16): lanes 0-15 src, 16-31 dst
    int idx;
    {
        long e = eb0 + wv * 16 + l15; if (e >= NE) e = NE - 1;
        idx = edge[(((lane >> 4) & 1) ? (long)NE : 0L) + e];
    }

    float b1v[4], w2v[4];
#pragma unroll
    for (int nf = 0; nf < 4; ++nf) {
        int col = ni * 64 + nf * 16 + l15;
        b1v[nf] = b1[col];
        w2v[nf] = W2[col];
    }
    const float bias2 = b2[0];

    // ---- gather + product -> swizzled x-tile rows [wv*16, wv*16+16) ----
    if (MIRROR) {
        half4 vs[8], vd[8];
#pragma unroll
        for (int b = 0; b < 2; ++b) {
#pragma unroll
            for (int j = 0; j < 8; ++j) {
                int s = __builtin_amdgcn_readlane(idx, b * 8 + j);
                int d = __builtin_amdgcn_readlane(idx, 16 + b * 8 + j);
                // one instr = one contiguous 512B node row (64 lanes x 8B)
                vs[j] = *reinterpret_cast<const half4*>(zi + (long)s * 256 + lane * 4);
                vd[j] = *reinterpret_cast<const half4*>(zi + (long)d * 256 + lane * 4);
            }
#pragma unroll
            for (int j = 0; j < 8; ++j) {
                int e = wv * 16 + b * 8 + j;
                half4 p = vs[j] * vd[j];                  // 2x v_pk_mul_f16
                *reinterpret_cast<half4*>(
                    (char*)xs + e * 512 + ((lane * 8) ^ ((e & 7) << 4))) = p;
            }
        }
    } else {
        const float* zs = (lane < 32) ? z : z2;
        const int coff = (lane & 31) * 4;
#pragma unroll
        for (int b = 0; b < 4; ++b) {
            float4 fs[4], fd[4];
#pragma unroll
            for (int j = 0; j < 4; ++j) {
                int s = __builtin_amdgcn_readlane(idx, b * 4 + j);
                int d = __builtin_amdgcn_readlane(idx, 16 + b * 4 + j);
                fs[j] = *reinterpret_cast<const float4*>(zs + (long)s * ND + coff);
                fd[j] = *reinterpret_cast<const float4*>(zs + (long)d * ND + coff);
            }
#pragma unroll
            for (int j = 0; j < 4; ++j) {
                int e = wv * 16 + b * 4 + j;
                half4 p;
                p[0] = (_Float16)(fs[j].x * fd[j].x);
                p[1] = (_Float16)(fs[j].y * fd[j].y);
                p[2] = (_Float16)(fs[j].z * fd[j].z);
                p[3] = (_Float16)(fs[j].w * fd[j].w);
                *reinterpret_cast<half4*>(
                    (char*)xs + e * 512 + ((lane * 8) ^ ((e & 7) << 4))) = p;
            }
        }
    }
    __syncthreads();

    // ---- MFMA: rows [mi*64, mi*64+64) x cols [ni*64, ni*64+64) ----
    f32x4 acc[4][4];
#pragma unroll
    for (int mf = 0; mf < 4; ++mf)
#pragma unroll
        for (int nf = 0; nf < 4; ++nf)
            acc[mf][nf] = (f32x4){b1v[nf], b1v[nf], b1v[nf], b1v[nf]};

#pragma unroll
    for (int ks = 0; ks < 8; ++ks) {
        const int kb = ks * 64 + l4 * 16;
        half8 a[4], bfr[4];
#pragma unroll
        for (int mf = 0; mf < 4; ++mf) {
            int r = mi * 64 + mf * 16 + l15;
            a[mf] = *reinterpret_cast<const half8*>(
                (const char*)xs + r * 512 + (kb ^ ((r & 7) << 4)));
        }
#pragma unroll
        for (int nf = 0; nf < 4; ++nf)
            bfr[nf] = *reinterpret_cast<const half8*>(
                w1p + (ni * 32 + nf * 8 + ks) * 512 + lane * 8);
#pragma unroll
        for (int mf = 0; mf < 4; ++mf)
#pragma unroll
            for (int nf = 0; nf < 4; ++nf)
                acc[mf][nf] = __builtin_amdgcn_mfma_f32_16x16x32_f16(
                    a[mf], bfr[nf], acc[mf][nf], 0, 0, 0);
    }

    // ---- epilogue: relu + W2-dot, butterfly reducing-transpose ----
    float v[16];
#pragma unroll
    for (int mf = 0; mf < 4; ++mf)
#pragma unroll
        for (int r = 0; r < 4; ++r) {
            float s = 0.f;
#pragma unroll
            for (int nf = 0; nf < 4; ++nf)
                s += fmaxf(acc[mf][nf][r], 0.f) * w2v[nf];
            v[mf * 4 + r] = s;
        }
#pragma unroll
    for (int j = 0; j < 4; ++j) {
        const int m = 1 << j;
        const bool hi = (l15 & m) != 0;
#pragma unroll
        for (int p = 0; p < 16; p += 2 * m) {
            float snd = hi ? v[p] : v[p + m];
            float rcv = __shfl_xor(snd, m, 64);
            float kept = hi ? v[p + m] : v[p];
            v[p] = kept + rcv;
        }
    }
    {
        int row = mi * 64 + (l15 >> 2) * 16 + l4 * 4 + (l15 & 3);
        ps[ni * 128 + row] = v[0];
    }
    __syncthreads();

    // ---- combine + sigmoid + store ----
    if (tid < 128) {
        float p = ps[tid] + ps[128 + tid] + ps[256 + tid] + ps[384 + tid] + bias2;
        long e = eb0 + tid;
        if (e < NE) out[e] = 1.0f / (1.0f + expf(-p));
    }
}

extern "C" void kernel_launch(void* const* d_in, const int* in_sizes, int n_in,
                              void* d_out, int out_size, void* d_ws, size_t ws_size,
                              hipStream_t stream)
{
    const float* z  = (const float*)d_in[0];
    const float* z2 = (const float*)d_in[1];
    const int*  edge = (const int*)d_in[2];
    const float* W1 = (const float*)d_in[3];
    const float* b1 = (const float*)d_in[4];
    const float* W2 = (const float*)d_in[5];
    const float* b2 = (const float*)d_in[6];
    float* out = (float*)d_out;

    const size_t zi_bytes = (size_t)NNODES * 256 * 2;        // 51.2 MB
    const size_t w1_bytes = 256 * 256 * 2;                   // 128 KB
    const bool mirrors = (ws_size >= zi_bytes + w1_bytes);

    _Float16* zi  = (_Float16*)d_ws;
    _Float16* w1p = mirrors ? (_Float16*)((char*)d_ws + zi_bytes)
                            : (_Float16*)d_ws;

    if (mirrors) {
        prep_all_kernel<<<ZI_BLOCKS + 256, 256, 0, stream>>>(z, z2, zi, W1, w1p);
        edge_mlp_v12<1><<<NT2, 512, 0, stream>>>(
            z, z2, zi, edge, w1p, b1, W2, b2, out);
    } else {
        prep_all_kernel<<<256, 256, 0, stream>>>(z, z2, (_Float16*)nullptr, W1, w1p);
        edge_mlp_v12<0><<<NT2, 512, 0, stream>>>(
            z, z2, (const _Float16*)nullptr, edge, w1p, b1, W2, b2, out);
    }
}

// Round 13
// 207.869 us; speedup vs baseline: 1.0502x; 1.0502x over previous
//
#include <hip/hip_runtime.h>
#include <hip/hip_bf16.h>
#include <math.h>

typedef _Float16 half4 __attribute__((ext_vector_type(4)));
typedef _Float16 half8 __attribute__((ext_vector_type(8)));
typedef float f32x4 __attribute__((ext_vector_type(4)));

#define NE 500000
#define ND 128
#define NNODES 100000
#define NT ((NE + 63) / 64)          // 7813 tiles of 64 edges
#define ZI_BLOCKS 12500
#define W1_BLOCKS 256
#define HIST_BLOCKS 977              // 512 edges per block
#define NB 12504                     // buckets of 8 nodes: key = src >> 3

// ---- K0: zero the histogram (fresh every launch; ws is not re-poisoned) ----
__global__ __launch_bounds__(256) void zero_hist_kernel(int* __restrict__ hist) {
    int i = blockIdx.x * 256 + threadIdx.x;
    if (i < NB) hist[i] = 0;
}

// ---- P1 merged prep: zi mirror | w1p pack | src histogram ----
// zi[node][256] = [z row | z2 row] fp16 (512B contiguous per node).
// w1p = W1 in MFMA B-frag order (see r9 comment).
__global__ __launch_bounds__(256) void prep_all_kernel(
    const float* __restrict__ z, const float* __restrict__ z2,
    _Float16* __restrict__ zi,
    const float* __restrict__ W1, _Float16* __restrict__ w1p,
    const int* __restrict__ edge, int* __restrict__ hist, int do_hist) {
    if (blockIdx.x < ZI_BLOCKS) {
        long t = (long)blockIdx.x * 256 + threadIdx.x;
        long idx = t * 8;
        int node = (int)(idx >> 8), col = (int)(idx & 255);
        const float* src = (col < 128) ? (z + (long)node * 128 + col)
                                       : (z2 + (long)node * 128 + (col - 128));
        float4 a = *reinterpret_cast<const float4*>(src);
        float4 b = *reinterpret_cast<const float4*>(src + 4);
        half8 v;
        v[0] = (_Float16)a.x; v[1] = (_Float16)a.y;
        v[2] = (_Float16)a.z; v[3] = (_Float16)a.w;
        v[4] = (_Float16)b.x; v[5] = (_Float16)b.y;
        v[6] = (_Float16)b.z; v[7] = (_Float16)b.w;
        *reinterpret_cast<half8*>(zi + idx) = v;
    } else if (blockIdx.x < ZI_BLOCKS + W1_BLOCKS) {
        int i = (blockIdx.x - ZI_BLOCKS) * 256 + threadIdx.x;
        int j = i & 7;
        int lane = (i >> 3) & 63;
        int ks = (i >> 9) & 7;
        int nf = (i >> 12) & 3;
        int ni = i >> 14;
        int col = ni * 64 + nf * 16 + (lane & 15);
        int k = ks * 32 + (lane >> 4) * 8 + j;
        w1p[i] = (_Float16)W1[(long)k * 256 + col];
    } else if (do_hist) {
        int h = blockIdx.x - ZI_BLOCKS - W1_BLOCKS;     // 0..976
        long e0 = (long)h * 512 + threadIdx.x;
#pragma unroll
        for (int r = 0; r < 2; ++r) {
            long e = e0 + r * 256;
            if (e < NE) atomicAdd(&hist[edge[e] >> 3], 1);
        }
    }
}

// ---- P2: single-block exclusive scan of 12504 bins -> cursor ----
__global__ __launch_bounds__(256) void scan_kernel(
    const int* __restrict__ hist, int* __restrict__ cursor) {
    __shared__ int part[256];
    const int t = threadIdx.x;
    const int base = t * 49;                 // 256*49 = 12544 >= NB
    int s = 0;
    for (int i = 0; i < 49; ++i) {
        int idx = base + i;
        if (idx < NB) s += hist[idx];
    }
    part[t] = s;
    __syncthreads();
    for (int off = 1; off < 256; off <<= 1) {
        int v = (t >= off) ? part[t - off] : 0;
        __syncthreads();
        part[t] += v;
        __syncthreads();
    }
    int run = (t == 0) ? 0 : part[t - 1];
    for (int i = 0; i < 49; ++i) {
        int idx = base + i;
        if (idx < NB) { cursor[idx] = run; run += hist[idx]; }
    }
}

// ---- P3: scatter edges into src-sorted order ----
__global__ __launch_bounds__(256) void scatter_kernel(
    const int* __restrict__ edge, int* __restrict__ cursor,
    int* __restrict__ ssrc, int* __restrict__ sdst, int* __restrict__ sorg) {
    long e = (long)blockIdx.x * 256 + threadIdx.x;
    if (e >= NE) return;
    int s = edge[e], d = edge[NE + e];
    int p = atomicAdd(&cursor[s >> 3], 1);
    ssrc[p] = s; sdst[p] = d; sorg[p] = (int)e;
}

// ---- main kernel: r11-proven structure. MODE 2: sorted+mirror,
//      MODE 1: mirror (r11 exact), MODE 0: f32 fallback. ----
template<int MODE>
__global__ __launch_bounds__(256, 4) void edge_mlp_v13(
    const float* __restrict__ z, const float* __restrict__ z2,
    const _Float16* __restrict__ zi,
    const int* __restrict__ edge,
    const int* __restrict__ ssrc, const int* __restrict__ sdst,
    const int* __restrict__ sorg,
    const _Float16* __restrict__ w1p,
    const float* __restrict__ b1, const float* __restrict__ W2,
    const float* __restrict__ b2, float* __restrict__ out)
{
    __shared__ _Float16 xs[64 * 256];   // 32 KB, XOR-swizzled x-tile
    __shared__ float ps[256];           // partials [ni][row]

    const int tid = threadIdx.x;
    const int lane = tid & 63;
    const int wv = tid >> 6;            // 0..3 == col quarter
    const int l15 = lane & 15;
    const int l4 = lane >> 4;
    const long eb0 = (long)blockIdx.x * 64;

    // wave's 16 edges: lanes 0-15 src idx, lanes 16-31 dst idx
    int idx;
    {
        long e = eb0 + wv * 16 + l15; if (e >= NE) e = NE - 1;
        if (MODE == 2)
            idx = ((lane >> 4) & 1) ? sdst[e] : ssrc[e];
        else
            idx = edge[(((lane >> 4) & 1) ? (long)NE : 0L) + e];
    }

    float b1v[4], w2v[4];
#pragma unroll
    for (int nf = 0; nf < 4; ++nf) {
        int col = wv * 64 + nf * 16 + l15;
        b1v[nf] = b1[col];
        w2v[nf] = W2[col];
    }
    const float bias2 = b2[0];

    // ---- gather + product -> swizzled x-tile rows [wv*16, wv*16+16) ----
    if (MODE >= 1) {
        half4 vs[8], vd[8];
#pragma unroll
        for (int b = 0; b < 2; ++b) {
#pragma unroll
            for (int j = 0; j < 8; ++j) {
                int s = __builtin_amdgcn_readlane(idx, b * 8 + j);
                int d = __builtin_amdgcn_readlane(idx, 16 + b * 8 + j);
                // one instr = one contiguous 512B node row (64 lanes x 8B)
                vs[j] = *reinterpret_cast<const half4*>(zi + (long)s * 256 + lane * 4);
                vd[j] = *reinterpret_cast<const half4*>(zi + (long)d * 256 + lane * 4);
            }
#pragma unroll
            for (int j = 0; j < 8; ++j) {
                int e = wv * 16 + b * 8 + j;
                half4 p = vs[j] * vd[j];                  // 2x v_pk_mul_f16
                *reinterpret_cast<half4*>(
                    (char*)xs + e * 512 + ((lane * 8) ^ ((e & 7) << 4))) = p;
            }
        }
    } else {
        const float* zs = (lane < 32) ? z : z2;
        const int coff = (lane & 31) * 4;
#pragma unroll
        for (int b = 0; b < 4; ++b) {
            float4 fs[4], fd[4];
#pragma unroll
            for (int j = 0; j < 4; ++j) {
                int s = __builtin_amdgcn_readlane(idx, b * 4 + j);
                int d = __builtin_amdgcn_readlane(idx, 16 + b * 4 + j);
                fs[j] = *reinterpret_cast<const float4*>(zs + (long)s * ND + coff);
                fd[j] = *reinterpret_cast<const float4*>(zs + (long)d * ND + coff);
            }
#pragma unroll
            for (int j = 0; j < 4; ++j) {
                int e = wv * 16 + b * 4 + j;
                half4 p;
                p[0] = (_Float16)(fs[j].x * fd[j].x);
                p[1] = (_Float16)(fs[j].y * fd[j].y);
                p[2] = (_Float16)(fs[j].z * fd[j].z);
                p[3] = (_Float16)(fs[j].w * fd[j].w);
                *reinterpret_cast<half4*>(
                    (char*)xs + e * 512 + ((lane * 8) ^ ((e & 7) << 4))) = p;
            }
        }
    }
    __syncthreads();

    // ---- MFMA: acc initialized with b1 (bias folded into C-input) ----
    f32x4 acc[4][4];
#pragma unroll
    for (int mf = 0; mf < 4; ++mf)
#pragma unroll
        for (int nf = 0; nf < 4; ++nf)
            acc[mf][nf] = (f32x4){b1v[nf], b1v[nf], b1v[nf], b1v[nf]};

#pragma unroll
    for (int ks = 0; ks < 8; ++ks) {
        const int kb = ks * 64 + l4 * 16;
        half8 a[4], bfr[4];
#pragma unroll
        for (int mf = 0; mf < 4; ++mf) {
            int r = mf * 16 + l15;
            a[mf] = *reinterpret_cast<const half8*>(
                (const char*)xs + r * 512 + (kb ^ ((r & 7) << 4)));
        }
#pragma unroll
        for (int nf = 0; nf < 4; ++nf)
            bfr[nf] = *reinterpret_cast<const half8*>(
                w1p + (wv * 32 + nf * 8 + ks) * 512 + lane * 8);
#pragma unroll
        for (int mf = 0; mf < 4; ++mf)
#pragma unroll
            for (int nf = 0; nf < 4; ++nf)
                acc[mf][nf] = __builtin_amdgcn_mfma_f32_16x16x32_f16(
                    a[mf], bfr[nf], acc[mf][nf], 0, 0, 0);
    }

    // ---- epilogue: relu + W2-dot, butterfly reducing-transpose ----
    float v[16];
#pragma unroll
    for (int mf = 0; mf < 4; ++mf)
#pragma unroll
        for (int r = 0; r < 4; ++r) {
            float s = 0.f;
#pragma unroll
            for (int nf = 0; nf < 4; ++nf)
                s += fmaxf(acc[mf][nf][r], 0.f) * w2v[nf];
            v[mf * 4 + r] = s;
        }
#pragma unroll
    for (int j = 0; j < 4; ++j) {
        const int m = 1 << j;
        const bool hi = (l15 & m) != 0;
#pragma unroll
        for (int p = 0; p < 16; p += 2 * m) {
            float snd = hi ? v[p] : v[p + m];
            float rcv = __shfl_xor(snd, m, 64);
            float kept = hi ? v[p + m] : v[p];
            v[p] = kept + rcv;
        }
    }
    {
        int row = (l15 >> 2) * 16 + l4 * 4 + (l15 & 3);
        ps[wv * 64 + row] = v[0];
    }
    __syncthreads();

    // ---- combine + sigmoid + store ----
    if (tid < 64) {
        float p = ps[tid] + ps[64 + tid] + ps[128 + tid] + ps[192 + tid] + bias2;
        long e = eb0 + tid;
        if (e < NE) {
            float r = 1.0f / (1.0f + expf(-p));
            if (MODE == 2) out[sorg[e]] = r;
            else           out[e] = r;
        }
    }
}

extern "C" void kernel_launch(void* const* d_in, const int* in_sizes, int n_in,
                              void* d_out, int out_size, void* d_ws, size_t ws_size,
                              hipStream_t stream)
{
    const float* z  = (const float*)d_in[0];
    const float* z2 = (const float*)d_in[1];
    const int*  edge = (const int*)d_in[2];
    const float* W1 = (const float*)d_in[3];
    const float* b1 = (const float*)d_in[4];
    const float* W2 = (const float*)d_in[5];
    const float* b2 = (const float*)d_in[6];
    float* out = (float*)d_out;

    // ws layout
    const size_t zi_b   = (size_t)NNODES * 256 * 2;          // 51.2 MB
    const size_t w1_b   = 256 * 256 * 2;                     // 128 KB
    const size_t sort_b = (size_t)NT * 64 * 4;               // 2.0 MB each
    const size_t hist_b = (size_t)NB * 4;                    // ~50 KB
    const size_t need_mirror = zi_b + w1_b;
    const size_t need_full   = need_mirror + 3 * sort_b + 2 * hist_b + 1024;

    char* p = (char*)d_ws;
    _Float16* zi  = (_Float16*)p;            p += zi_b;
    _Float16* w1p = (_Float16*)p;            p += w1_b;
    int* ssrc   = (int*)p;                   p += sort_b;
    int* sdst   = (int*)p;                   p += sort_b;
    int* sorg   = (int*)p;                   p += sort_b;
    int* hist   = (int*)p;                   p += hist_b;
    int* cursor = (int*)p;

    if (ws_size >= need_full) {
        zero_hist_kernel<<<(NB + 255) / 256, 256, 0, stream>>>(hist);
        prep_all_kernel<<<ZI_BLOCKS + W1_BLOCKS + HIST_BLOCKS, 256, 0, stream>>>(
            z, z2, zi, W1, w1p, edge, hist, 1);
        scan_kernel<<<1, 256, 0, stream>>>(hist, cursor);
        scatter_kernel<<<(NE + 255) / 256, 256, 0, stream>>>(
            edge, cursor, ssrc, sdst, sorg);
        edge_mlp_v13<2><<<NT, 256, 0, stream>>>(
            z, z2, zi, edge, ssrc, sdst, sorg, w1p, b1, W2, b2, out);
    } else if (ws_size >= need_mirror) {
        _Float16* w1p2 = (_Float16*)((char*)d_ws + zi_b);
        prep_all_kernel<<<ZI_BLOCKS + W1_BLOCKS, 256, 0, stream>>>(
            z, z2, zi, W1, w1p2, edge, (int*)nullptr, 0);
        edge_mlp_v13<1><<<NT, 256, 0, stream>>>(
            z, z2, zi, edge, nullptr, nullptr, nullptr, w1p2, b1, W2, b2, out);
    } else {
        _Float16* w1p2 = (_Float16*)d_ws;    // 128 KB only
        prep_all_kernel<<<ZI_BLOCKS + W1_BLOCKS, 256, 0, stream>>>(
            z, z2, (_Float16*)nullptr, W1, w1p2, edge, (int*)nullptr, 0);
        edge_mlp_v13<0><<<NT, 256, 0, stream>>>(
            z, z2, nullptr, edge, nullptr, nullptr, nullptr, w1p2, b1, W2, b2, out);
    }
}

// Round 14
// 131.610 us; speedup vs baseline: 1.6588x; 1.5794x over previous
//
#include <hip/hip_runtime.h>
#include <hip/hip_bf16.h>
#include <math.h>

typedef _Float16 half4 __attribute__((ext_vector_type(4)));
typedef _Float16 half8 __attribute__((ext_vector_type(8)));
typedef float f32x4 __attribute__((ext_vector_type(4)));

#define NE 500000
#define ND 128
#define NNODES 100000
#define NT ((NE + 63) / 64)          // 7813 tiles of 64 edges
#define ZI_BLOCKS 12500              // prep: zi mirror part

// ---- merged prep: blocks [0,12500) build zi; [12500,12756) build w1p ----
// zi[node][256] = [z row | z2 row] fp16, contiguous 512B per node.
// w1p = W1 packed in MFMA B-frag order: i = ni*16384+nf*4096+ks*512+lane*8+j
//   holds W1[k][col], col = ni*64+nf*16+(lane&15), k = ks*32+(lane>>4)*8+j.
__global__ __launch_bounds__(256) void prep_all_kernel(
    const float* __restrict__ z, const float* __restrict__ z2,
    _Float16* __restrict__ zi,
    const float* __restrict__ W1, _Float16* __restrict__ w1p) {
    if (blockIdx.x < ZI_BLOCKS) {
        long t = (long)blockIdx.x * 256 + threadIdx.x;  // 3.2M threads, 8 elems
        long idx = t * 8;
        int node = (int)(idx >> 8), col = (int)(idx & 255);
        const float* src = (col < 128) ? (z + (long)node * 128 + col)
                                       : (z2 + (long)node * 128 + (col - 128));
        float4 a = *reinterpret_cast<const float4*>(src);
        float4 b = *reinterpret_cast<const float4*>(src + 4);
        half8 v;
        v[0] = (_Float16)a.x; v[1] = (_Float16)a.y;
        v[2] = (_Float16)a.z; v[3] = (_Float16)a.w;
        v[4] = (_Float16)b.x; v[5] = (_Float16)b.y;
        v[6] = (_Float16)b.z; v[7] = (_Float16)b.w;
        *reinterpret_cast<half8*>(zi + idx) = v;
    } else {
        int i = (blockIdx.x - ZI_BLOCKS) * 256 + threadIdx.x;   // 0..65535
        int j = i & 7;
        int lane = (i >> 3) & 63;
        int ks = (i >> 9) & 7;
        int nf = (i >> 12) & 3;
        int ni = i >> 14;
        int col = ni * 64 + nf * 16 + (lane & 15);
        int k = ks * 32 + (lane >> 4) * 8 + j;
        w1p[i] = (_Float16)W1[(long)k * 256 + col];
    }
}

// v14 == r11 (proven 132 us): 256 thr / 4 waves, 16 waves/CU, single-segment
// 512B row gathers from the interleaved fp16 mirror, B-frags from packed
// L2-resident w1p, b1 folded into MFMA C-init, butterfly epilogue.
template<int MIRROR>
__global__ __launch_bounds__(256, 4) void edge_mlp_v14(
    const float* __restrict__ z, const float* __restrict__ z2,
    const _Float16* __restrict__ zi,
    const int* __restrict__ edge,
    const _Float16* __restrict__ w1p,
    const float* __restrict__ b1, const float* __restrict__ W2,
    const float* __restrict__ b2, float* __restrict__ out)
{
    __shared__ _Float16 xs[64 * 256];   // 32 KB, XOR-swizzled x-tile
    __shared__ float ps[256];           // 1 KB partials [ni][row]

    const int tid = threadIdx.x;
    const int lane = tid & 63;
    const int wv = tid >> 6;            // 0..3 == col quarter
    const int l15 = lane & 15;
    const int l4 = lane >> 4;
    const long eb0 = (long)blockIdx.x * 64;

    // wave's 16 edges: lanes 0-15 src idx, lanes 16-31 dst idx
    int idx;
    {
        long e = eb0 + wv * 16 + l15; if (e >= NE) e = NE - 1;
        idx = edge[(((lane >> 4) & 1) ? (long)NE : 0L) + e];
    }

    float b1v[4], w2v[4];
#pragma unroll
    for (int nf = 0; nf < 4; ++nf) {
        int col = wv * 64 + nf * 16 + l15;
        b1v[nf] = b1[col];
        w2v[nf] = W2[col];
    }
    const float bias2 = b2[0];

    // ---- gather + product -> swizzled x-tile rows [wv*16, wv*16+16) ----
    if (MIRROR) {
        half4 vs[8], vd[8];
#pragma unroll
        for (int b = 0; b < 2; ++b) {
#pragma unroll
            for (int j = 0; j < 8; ++j) {
                int s = __builtin_amdgcn_readlane(idx, b * 8 + j);
                int d = __builtin_amdgcn_readlane(idx, 16 + b * 8 + j);
                // one instr = one contiguous 512B node row (64 lanes x 8B)
                vs[j] = *reinterpret_cast<const half4*>(zi + (long)s * 256 + lane * 4);
                vd[j] = *reinterpret_cast<const half4*>(zi + (long)d * 256 + lane * 4);
            }
#pragma unroll
            for (int j = 0; j < 8; ++j) {
                int e = wv * 16 + b * 8 + j;
                half4 p = vs[j] * vd[j];                  // 2x v_pk_mul_f16
                *reinterpret_cast<half4*>(
                    (char*)xs + e * 512 + ((lane * 8) ^ ((e & 7) << 4))) = p;
            }
        }
    } else {
        const float* zs = (lane < 32) ? z : z2;
        const int coff = (lane & 31) * 4;
#pragma unroll
        for (int b = 0; b < 4; ++b) {
            float4 fs[4], fd[4];
#pragma unroll
            for (int j = 0; j < 4; ++j) {
                int s = __builtin_amdgcn_readlane(idx, b * 4 + j);
                int d = __builtin_amdgcn_readlane(idx, 16 + b * 4 + j);
                fs[j] = *reinterpret_cast<const float4*>(zs + (long)s * ND + coff);
                fd[j] = *reinterpret_cast<const float4*>(zs + (long)d * ND + coff);
            }
#pragma unroll
            for (int j = 0; j < 4; ++j) {
                int e = wv * 16 + b * 4 + j;
                half4 p;
                p[0] = (_Float16)(fs[j].x * fd[j].x);
                p[1] = (_Float16)(fs[j].y * fd[j].y);
                p[2] = (_Float16)(fs[j].z * fd[j].z);
                p[3] = (_Float16)(fs[j].w * fd[j].w);
                *reinterpret_cast<half4*>(
                    (char*)xs + e * 512 + ((lane * 8) ^ ((e & 7) << 4))) = p;
            }
        }
    }
    __syncthreads();

    // ---- MFMA: acc initialized with b1 (bias folded into C-input) ----
    f32x4 acc[4][4];
#pragma unroll
    for (int mf = 0; mf < 4; ++mf)
#pragma unroll
        for (int nf = 0; nf < 4; ++nf)
            acc[mf][nf] = (f32x4){b1v[nf], b1v[nf], b1v[nf], b1v[nf]};

#pragma unroll
    for (int ks = 0; ks < 8; ++ks) {
        const int kb = ks * 64 + l4 * 16;
        half8 a[4], bfr[4];
#pragma unroll
        for (int mf = 0; mf < 4; ++mf) {
            int r = mf * 16 + l15;
            a[mf] = *reinterpret_cast<const half8*>(
                (const char*)xs + r * 512 + (kb ^ ((r & 7) << 4)));
        }
#pragma unroll
        for (int nf = 0; nf < 4; ++nf)
            bfr[nf] = *reinterpret_cast<const half8*>(
                w1p + (wv * 32 + nf * 8 + ks) * 512 + lane * 8);
#pragma unroll
        for (int mf = 0; mf < 4; ++mf)
#pragma unroll
            for (int nf = 0; nf < 4; ++nf)
                acc[mf][nf] = __builtin_amdgcn_mfma_f32_16x16x32_f16(
                    a[mf], bfr[nf], acc[mf][nf], 0, 0, 0);
    }

    // ---- epilogue: relu + W2-dot, butterfly reducing-transpose.
    // After 4 levels lane l15 holds the sum for row (l15>>2)*16+l4*4+(l15&3).
    float v[16];
#pragma unroll
    for (int mf = 0; mf < 4; ++mf)
#pragma unroll
        for (int r = 0; r < 4; ++r) {
            float s = 0.f;
#pragma unroll
            for (int nf = 0; nf < 4; ++nf)
                s += fmaxf(acc[mf][nf][r], 0.f) * w2v[nf];
            v[mf * 4 + r] = s;
        }
#pragma unroll
    for (int j = 0; j < 4; ++j) {
        const int m = 1 << j;
        const bool hi = (l15 & m) != 0;
#pragma unroll
        for (int p = 0; p < 16; p += 2 * m) {
            float snd = hi ? v[p] : v[p + m];
            float rcv = __shfl_xor(snd, m, 64);
            float kept = hi ? v[p + m] : v[p];
            v[p] = kept + rcv;
        }
    }
    {
        int row = (l15 >> 2) * 16 + l4 * 4 + (l15 & 3);
        ps[wv * 64 + row] = v[0];
    }
    __syncthreads();

    // ---- combine + sigmoid + store ----
    if (tid < 64) {
        float p = ps[tid] + ps[64 + tid] + ps[128 + tid] + ps[192 + tid] + bias2;
        long e = eb0 + tid;
        if (e < NE) out[e] = 1.0f / (1.0f + expf(-p));
    }
}

extern "C" void kernel_launch(void* const* d_in, const int* in_sizes, int n_in,
                              void* d_out, int out_size, void* d_ws, size_t ws_size,
                              hipStream_t stream)
{
    const float* z  = (const float*)d_in[0];
    const float* z2 = (const float*)d_in[1];
    const int*  edge = (const int*)d_in[2];
    const float* W1 = (const float*)d_in[3];
    const float* b1 = (const float*)d_in[4];
    const float* W2 = (const float*)d_in[5];
    const float* b2 = (const float*)d_in[6];
    float* out = (float*)d_out;

    const size_t zi_bytes = (size_t)NNODES * 256 * 2;        // 51.2 MB
    const size_t w1_bytes = 256 * 256 * 2;                   // 128 KB
    const bool mirrors = (ws_size >= zi_bytes + w1_bytes);

    _Float16* zi  = (_Float16*)d_ws;
    _Float16* w1p = mirrors ? (_Float16*)((char*)d_ws + zi_bytes)
                            : (_Float16*)d_ws;

    if (mirrors) {
        prep_all_kernel<<<ZI_BLOCKS + 256, 256, 0, stream>>>(z, z2, zi, W1, w1p);
        edge_mlp_v14<1><<<NT, 256, 0, stream>>>(
            z, z2, zi, edge, w1p, b1, W2, b2, out);
    } else {
        prep_all_kernel<<<256, 256, 0, stream>>>(z, z2, (_Float16*)nullptr, W1, w1p);
        edge_mlp_v14<0><<<NT, 256, 0, stream>>>(
            z, z2, (const _Float16*)nullptr, edge, w1p, b1, W2, b2, out);
    }
}